// Round 2
// baseline (218.001 us; speedup 1.0000x reference)
//
#include <hip/hip_runtime.h>
#include <math.h>

typedef float v2 __attribute__((ext_vector_type(2)));

// B=128, IN=256, H=1024 -> 128 steps of (layerA, layerB). nA=512, nB=511.
#define NBATCH 128
#define NIN    256
#define NH     1024
#define NSTEPS 128
#define NB     511

// Angle table: [layer][j(0..3)][g(0..255)] float4 {c0,s0,c1,s1}
//   g = global lane (4 waves x 64 lanes), owns channels 4g..4g+3
//   j=0: A pair 2g     (ch 4g,4g+1)
//   j=1: A pair 2g+1   (ch 4g+2,4g+3)
//   j=2: B pair 2g     (ch 4g+1,4g+2)   always valid (2g <= 510)
//   j=3: B pair 2g+1   (ch 4g+3,4g+4)   g=255 -> pair 511 -> identity
// Left-boundary angle for lane g is entry (j=3, g-1): loaded directly
// (prefetchable). Table = 2 MB; ih = 1 MB.
#define TAB_F4_PER_L 1024
#define IH_OFF (NSTEPS * TAB_F4_PER_L * 4)   // float offset; ih float4 = {R,I,R,I}

#define GEMM_BLOCKS 256
#define TRIG_BLOCKS 512                      // 512*256 = 128*1024 exactly

static __device__ __forceinline__ v2 to2(float a, float b) { v2 r; r.x = a; r.y = b; return r; }

// ---------------------------------------------------------------------------
// prep: blocks [0,256) complex gemm ih = in @ W^T + bias; [256,768) trig table
// ---------------------------------------------------------------------------
__global__ __launch_bounds__(256) void prep_kernel(
    const float* __restrict__ inR, const float* __restrict__ inI,
    const float* __restrict__ wR,  const float* __restrict__ wI,
    const float* __restrict__ biasR, const float* __restrict__ biasI,
    const float* __restrict__ A0, const float* __restrict__ A1,
    const float* __restrict__ B0, const float* __restrict__ B1,
    float* __restrict__ ws)
{
    __shared__ v2 xs[256][17];   // [k][b]  {xr,xi}
    __shared__ v2 wsh[32][34];   // [k][h]  {wr,wi}; stride 34 v2 = 272 B (16-aligned rows)

    if (blockIdx.x >= GEMM_BLOCKS) {
        // ---------------- trig branch ----------------
        int idx = (blockIdx.x - GEMM_BLOCKS) * 256 + threadIdx.x;
        int l = idx >> 10;
        int s = idx & 1023;
        int j = s >> 8, g = s & 255;
        float a0, a1;
        bool ident = false;
        if (j < 2) {
            int p = 2 * g + j;                    // A pair, always < 512
            a0 = A0[l * 512 + p]; a1 = A1[l * 512 + p];
        } else {
            int p = 2 * g + (j - 2);              // B pair
            if (p < NB) { a0 = B0[l * NB + p]; a1 = B1[l * NB + p]; }
            else ident = true;
        }
        float4 v;
        if (ident) v = make_float4(1.f, 0.f, 1.f, 0.f);
        else {
            float s0, c0, s1, c1;
            __sincosf(a0, &s0, &c0);
            __sincosf(a1, &s1, &c1);
            v = make_float4(c0, s0, c1, s1);
        }
        ((float4*)ws)[l * TAB_F4_PER_L + j * 256 + g] = v;
        return;
    }

    // ---------------- gemm branch: 32h x 16b tile ----------------
    const int ht = blockIdx.x >> 3, bt = blockIdx.x & 7;
    const int h0 = ht * 32, b0 = bt * 16;
    const int tid = threadIdx.x;

    // stage inputs for 16 batch rows: xs[k][b] = {inR, inI}
    {
        int b = tid >> 4, k4 = tid & 15;
#pragma unroll
        for (int p = 0; p < 4; ++p) {
            int k0 = p * 64 + k4 * 4;
            float4 vr = *(const float4*)(inR + (b0 + b) * NIN + k0);
            float4 vi = *(const float4*)(inI + (b0 + b) * NIN + k0);
            xs[k0 + 0][b] = to2(vr.x, vi.x);
            xs[k0 + 1][b] = to2(vr.y, vi.y);
            xs[k0 + 2][b] = to2(vr.z, vi.z);
            xs[k0 + 3][b] = to2(vr.w, vi.w);
        }
    }

    const int hg = tid & 15, bl = tid >> 4;   // thread: 2 h (h0+2hg, +1), 1 b
    v2 acc0 = to2(0.f, 0.f), acc1 = to2(0.f, 0.f);

    for (int c = 0; c < 8; ++c) {
        __syncthreads();
        // stage weight chunk: 32 h x 32 k as {wr,wi}
        {
            int hh = tid >> 3, k4 = tid & 7;
            float4 vr = *(const float4*)(wR + (h0 + hh) * NIN + c * 32 + k4 * 4);
            float4 vi = *(const float4*)(wI + (h0 + hh) * NIN + c * 32 + k4 * 4);
            wsh[k4 * 4 + 0][hh] = to2(vr.x, vi.x);
            wsh[k4 * 4 + 1][hh] = to2(vr.y, vi.y);
            wsh[k4 * 4 + 2][hh] = to2(vr.z, vi.z);
            wsh[k4 * 4 + 3][hh] = to2(vr.w, vi.w);
        }
        __syncthreads();
#pragma unroll
        for (int k = 0; k < 32; ++k) {
            float4 wv = *(const float4*)&wsh[k][hg * 2];   // {wr0,wi0,wr1,wi1}
            v2 w0 = to2(wv.x, wv.y), w1 = to2(wv.z, wv.w);
            v2 xv = xs[c * 32 + k][bl];
            acc0 += to2(xv.x, xv.x) * w0 + to2(xv.y, xv.y) * to2(-w0.y, w0.x);
            acc1 += to2(xv.x, xv.x) * w1 + to2(xv.y, xv.y) * to2(-w1.y, w1.x);
        }
    }
    int h = h0 + hg * 2, b = b0 + bl;
    acc0 += to2(biasR[h], biasI[h]);
    acc1 += to2(biasR[h + 1], biasI[h + 1]);
    ((float4*)(ws + IH_OFF))[b * 512 + (h >> 1)] =
        make_float4(acc0.x, acc0.y, acc1.x, acc1.y);
}

// ---------------------------------------------------------------------------
// mesh: 4 waves per batch row, 4 channels/lane. Intra-wave boundaries via
// shuffle; inter-wave boundaries via LDS + neighbor-local flag sync (NO
// workgroup barrier in the step loop). Data slots double-buffered by step
// parity; mutual dependency bounds wave slippage to <1 step, so 2 slots
// suffice. Flags are monotonic step counters.
// ---------------------------------------------------------------------------
__device__ __forceinline__ void mzi(const float4 t, v2& a, v2& b)
{
    // p = e^{i t0} a ; a' = c1 p + i s1 b ; b' = i s1 p + c1 b
    v2 P  = to2(t.x, t.y) * to2(a.x, a.x) + to2(-t.y, t.x) * to2(a.y, a.y);
    v2 na = to2(t.z, t.z) * P + to2(-t.w, t.w) * to2(b.y, b.x);
    b     = to2(t.z, t.z) * b + to2(-t.w, t.w) * to2(P.y, P.x);
    a = na;
}

// boundary bd (0..2) sits between wave bd and wave bd+1.
// vX0[par][bd] = post-A x[0] of wave bd+1 (lane 0)  -> read by wave bd lane 63
// vX3[par][bd] = post-A x[3] of wave bd   (lane 63) -> read by wave bd+1 lane 0
__device__ __forceinline__ void stepf(v2 x[4], const float4* T, const float4 TL,
                                      int w, int lane, int par, int l,
                                      volatile float (*vX0)[3][2],
                                      volatile float (*vX3)[3][2],
                                      volatile int* fX0, volatile int* fX3)
{
    // A layer: both pairs lane-local
    mzi(T[0], x[0], x[1]);
    mzi(T[1], x[2], x[3]);
    // publish post-A boundary values for neighbors
    if (lane == 0 && w > 0)  { vX0[par][w - 1][0] = x[0].x; vX0[par][w - 1][1] = x[0].y; }
    if (lane == 63 && w < 3) { vX3[par][w][0] = x[3].x;     vX3[par][w][1] = x[3].y; }
    __asm__ volatile("s_waitcnt lgkmcnt(0)" ::: "memory");   // data before flag
    if (lane == 0 && w > 0)  fX0[w - 1] = l + 1;
    if (lane == 63 && w < 3) fX3[w] = l + 1;

    // intra-wave boundary values via shuffle
    float rcr = __shfl_down(x[0].x, 1, 64);
    float rci = __shfl_down(x[0].y, 1, 64);
    float lcr = __shfl_up(x[3].x, 1, 64);
    float lci = __shfl_up(x[3].y, 1, 64);

    // B local pair (ch 4g+1, 4g+2) -- independent of boundary data, do it
    // while (potentially) waiting for neighbors
    mzi(T[2], x[1], x[2]);

    // neighbor-local spin (uniform per wave; typically already satisfied)
    if (w == 0)      { while (fX0[0] < l + 1) {} }
    else if (w == 3) { while (fX3[2] < l + 1) {} }
    else             { while (fX0[w] < l + 1 || fX3[w - 1] < l + 1) {} }

    // boundary lanes pick up neighbor values from LDS
    if (lane == 63 && w < 3) { rcr = vX0[par][w][0]; rci = vX0[par][w][1]; }
    if (lane == 0 && w > 0)  { lcr = vX3[par][w - 1][0]; lci = vX3[par][w - 1][1]; }

    // right boundary: a-side update of x[3] with neighbor's post-A x0
    {
        const float4 t = T[3];   // g=255: identity from table -> x3 unchanged
        v2 P = to2(t.x, t.y) * to2(x[3].x, x[3].x) + to2(-t.y, t.x) * to2(x[3].y, x[3].y);
        x[3] = to2(t.z, t.z) * P + to2(-t.w, t.w) * to2(rci, rcr);
    }
    // left boundary: b-side update of x[0] with left's post-A x3
    {
        // TL: g=0 -> identity -> x0 unchanged
        v2 P = to2(TL.x, TL.y) * to2(lcr, lcr) + to2(-TL.y, TL.x) * to2(lci, lci);
        x[0] = to2(TL.z, TL.z) * x[0] + to2(-TL.w, TL.w) * to2(P.y, P.x);
    }
}

#define LOADL(T, TL, l)                                                   \
    do {                                                                  \
        const float4* _p = tab + (l) * TAB_F4_PER_L + g;                  \
        T[0] = _p[0];                                                     \
        T[1] = _p[256];                                                   \
        T[2] = _p[512];                                                   \
        T[3] = _p[768];                                                   \
        TL = _p[767];                       /* (j=3, g-1) */              \
        if (g == 0) TL = make_float4(1.f, 0.f, 1.f, 0.f);                 \
    } while (0)

__global__ __launch_bounds__(256, 1) void mesh_kernel(
    const float* __restrict__ stateR, const float* __restrict__ stateI,
    const float* __restrict__ omega,  const float* __restrict__ mod_bias,
    const float* __restrict__ ws, float* __restrict__ out)
{
    const int b = blockIdx.x;
    const int g = threadIdx.x;         // global lane 0..255, channels 4g..4g+3
    const int lane = g & 63;
    const int w = g >> 6;
    const float4* tab = (const float4*)ws;

    __shared__ float vX0s[2][3][2];
    __shared__ float vX3s[2][3][2];
    __shared__ int fX0s[3], fX3s[3];
    volatile float (*vX0)[3][2] = vX0s;
    volatile float (*vX3)[3][2] = vX3s;
    volatile int* fX0 = fX0s;
    volatile int* fX3 = fX3s;

    if (g < 3) { fX0s[g] = 0; fX3s[g] = 0; }
    __syncthreads();   // once, before the step loop

    v2 x[4];
    {
        float4 r = *(const float4*)(stateR + b * NH + 4 * g);
        float4 i = *(const float4*)(stateI + b * NH + 4 * g);
        x[0] = to2(r.x, i.x);
        x[1] = to2(r.y, i.y);
        x[2] = to2(r.z, i.z);
        x[3] = to2(r.w, i.w);
    }

    float4 Ta[4], Tb[4], TLa, TLb;
    LOADL(Ta, TLa, 0);
    for (int l = 0; l < NSTEPS; l += 2) {
        LOADL(Tb, TLb, l + 1);
        stepf(x, Ta, TLa, w, lane, 0, l, vX0, vX3, fX0, fX3);
        {
            int ln = (l + 2 < NSTEPS) ? l + 2 : NSTEPS - 1;
            LOADL(Ta, TLa, ln);
        }
        stepf(x, Tb, TLb, w, lane, 1, l + 1, vX0, vX3, fX0, fX3);
    }

    // epilogue: phase, + ih, modReLU  (channels 4g..4g+3)
    float4 o4 = *(const float4*)(omega + 4 * g);
    float4 m4 = *(const float4*)(mod_bias + 4 * g);
    const float4* ihp = (const float4*)(ws + IH_OFF) + b * 512 + 2 * g;
    float4 ih0 = ihp[0], ih1 = ihp[1];   // {R,I,R,I} ch 4g,4g+1 / 4g+2,4g+3

    float om[4] = { o4.x, o4.y, o4.z, o4.w };
    float mb[4] = { m4.x, m4.y, m4.z, m4.w };
    float ihr[4] = { ih0.x, ih0.z, ih1.x, ih1.z };
    float ihi[4] = { ih0.y, ih0.w, ih1.y, ih1.w };
    float oR[4], oI[4];
#pragma unroll
    for (int j = 0; j < 4; ++j) {
        float so, co;
        __sincosf(om[j], &so, &co);
        float zr = ihr[j] + co * x[j].x - so * x[j].y;
        float zi = ihi[j] + so * x[j].x + co * x[j].y;
        float mag = sqrtf(zr * zr + zi * zi);
        float sc = fmaxf(mag + mb[j], 0.f) / fmaxf(mag, 1e-8f);
        oR[j] = sc * zr;
        oI[j] = sc * zi;
    }
    *(float4*)(out + b * NH + 4 * g) = make_float4(oR[0], oR[1], oR[2], oR[3]);
    *(float4*)(out + NBATCH * NH + b * NH + 4 * g) = make_float4(oI[0], oI[1], oI[2], oI[3]);
}

// ---------------------------------------------------------------------------
extern "C" void kernel_launch(void* const* d_in, const int* in_sizes, int n_in,
                              void* d_out, int out_size, void* d_ws, size_t ws_size,
                              hipStream_t stream)
{
    const float* inputsR = (const float*)d_in[0];
    const float* inputsI = (const float*)d_in[1];
    const float* stateR  = (const float*)d_in[2];
    const float* stateI  = (const float*)d_in[3];
    const float* weightR = (const float*)d_in[4];
    const float* weightI = (const float*)d_in[5];
    const float* biasR   = (const float*)d_in[6];
    const float* biasI   = (const float*)d_in[7];
    const float* angleA0 = (const float*)d_in[8];
    const float* angleA1 = (const float*)d_in[9];
    const float* angleB0 = (const float*)d_in[10];
    const float* angleB1 = (const float*)d_in[11];
    const float* omega   = (const float*)d_in[12];
    const float* mod_b   = (const float*)d_in[13];
    float* ws = (float*)d_ws;
    float* out = (float*)d_out;

    hipLaunchKernelGGL(prep_kernel, dim3(GEMM_BLOCKS + TRIG_BLOCKS), dim3(256),
                       0, stream, inputsR, inputsI, weightR, weightI,
                       biasR, biasI, angleA0, angleA1, angleB0, angleB1, ws);
    hipLaunchKernelGGL(mesh_kernel, dim3(NBATCH), dim3(256), 0, stream,
                       stateR, stateI, omega, mod_b, ws, out);
}

// Round 3
// 162.331 us; speedup vs baseline: 1.3429x; 1.3429x over previous
//
#include <hip/hip_runtime.h>
#include <math.h>

typedef float v2 __attribute__((ext_vector_type(2)));

// B=128, IN=256, H=1024 -> 128 steps of (layerA, layerB). nA=512, nB=511.
#define NBATCH 128
#define NIN    256
#define NH     1024
#define NSTEPS 128
#define NB     511

// Angle table: [layer][j(0..3)][g(0..255)] float4 {c0,s0,c1,s1}
//   g = global lane (4 waves x 64 lanes), owns channels 4g..4g+3
//   j=0: A pair 2g     (ch 4g,4g+1)
//   j=1: A pair 2g+1   (ch 4g+2,4g+3)
//   j=2: B pair 2g     (ch 4g+1,4g+2)   always valid (2g <= 510)
//   j=3: B pair 2g+1   (ch 4g+3,4g+4)   g=255 -> pair 511 -> identity
// Left-boundary angle for lane g is entry (j=3, g-1): loaded directly
// (prefetchable). Table = 2 MB; ih = 1 MB.
#define TAB_F4_PER_L 1024
#define IH_OFF (NSTEPS * TAB_F4_PER_L * 4)   // float offset; ih float4 = {R,I,R,I}

#define GEMM_BLOCKS 256
#define TRIG_BLOCKS 512                      // 512*256 = 128*1024 exactly

static __device__ __forceinline__ v2 to2(float a, float b) { v2 r; r.x = a; r.y = b; return r; }

// ---------------------------------------------------------------------------
// prep: blocks [0,256) complex gemm ih = in @ W^T + bias; [256,768) trig table
// ---------------------------------------------------------------------------
__global__ __launch_bounds__(256) void prep_kernel(
    const float* __restrict__ inR, const float* __restrict__ inI,
    const float* __restrict__ wR,  const float* __restrict__ wI,
    const float* __restrict__ biasR, const float* __restrict__ biasI,
    const float* __restrict__ A0, const float* __restrict__ A1,
    const float* __restrict__ B0, const float* __restrict__ B1,
    float* __restrict__ ws)
{
    __shared__ v2 xs[256][17];   // [k][b]  {xr,xi}
    __shared__ v2 wsh[32][34];   // [k][h]  {wr,wi}; stride 34 v2 = 272 B (16-aligned rows)

    if (blockIdx.x >= GEMM_BLOCKS) {
        // ---------------- trig branch ----------------
        int idx = (blockIdx.x - GEMM_BLOCKS) * 256 + threadIdx.x;
        int l = idx >> 10;
        int s = idx & 1023;
        int j = s >> 8, g = s & 255;
        float a0, a1;
        bool ident = false;
        if (j < 2) {
            int p = 2 * g + j;                    // A pair, always < 512
            a0 = A0[l * 512 + p]; a1 = A1[l * 512 + p];
        } else {
            int p = 2 * g + (j - 2);              // B pair
            if (p < NB) { a0 = B0[l * NB + p]; a1 = B1[l * NB + p]; }
            else ident = true;
        }
        float4 v;
        if (ident) v = make_float4(1.f, 0.f, 1.f, 0.f);
        else {
            float s0, c0, s1, c1;
            __sincosf(a0, &s0, &c0);
            __sincosf(a1, &s1, &c1);
            v = make_float4(c0, s0, c1, s1);
        }
        ((float4*)ws)[l * TAB_F4_PER_L + j * 256 + g] = v;
        return;
    }

    // ---------------- gemm branch: 32h x 16b tile ----------------
    const int ht = blockIdx.x >> 3, bt = blockIdx.x & 7;
    const int h0 = ht * 32, b0 = bt * 16;
    const int tid = threadIdx.x;

    // stage inputs for 16 batch rows: xs[k][b] = {inR, inI}
    {
        int b = tid >> 4, k4 = tid & 15;
#pragma unroll
        for (int p = 0; p < 4; ++p) {
            int k0 = p * 64 + k4 * 4;
            float4 vr = *(const float4*)(inR + (b0 + b) * NIN + k0);
            float4 vi = *(const float4*)(inI + (b0 + b) * NIN + k0);
            xs[k0 + 0][b] = to2(vr.x, vi.x);
            xs[k0 + 1][b] = to2(vr.y, vi.y);
            xs[k0 + 2][b] = to2(vr.z, vi.z);
            xs[k0 + 3][b] = to2(vr.w, vi.w);
        }
    }

    const int hg = tid & 15, bl = tid >> 4;   // thread: 2 h (h0+2hg, +1), 1 b
    v2 acc0 = to2(0.f, 0.f), acc1 = to2(0.f, 0.f);

    for (int c = 0; c < 8; ++c) {
        __syncthreads();
        // stage weight chunk: 32 h x 32 k as {wr,wi}
        {
            int hh = tid >> 3, k4 = tid & 7;
            float4 vr = *(const float4*)(wR + (h0 + hh) * NIN + c * 32 + k4 * 4);
            float4 vi = *(const float4*)(wI + (h0 + hh) * NIN + c * 32 + k4 * 4);
            wsh[k4 * 4 + 0][hh] = to2(vr.x, vi.x);
            wsh[k4 * 4 + 1][hh] = to2(vr.y, vi.y);
            wsh[k4 * 4 + 2][hh] = to2(vr.z, vi.z);
            wsh[k4 * 4 + 3][hh] = to2(vr.w, vi.w);
        }
        __syncthreads();
#pragma unroll
        for (int k = 0; k < 32; ++k) {
            float4 wv = *(const float4*)&wsh[k][hg * 2];   // {wr0,wi0,wr1,wi1}
            v2 w0 = to2(wv.x, wv.y), w1 = to2(wv.z, wv.w);
            v2 xv = xs[c * 32 + k][bl];
            acc0 += to2(xv.x, xv.x) * w0 + to2(xv.y, xv.y) * to2(-w0.y, w0.x);
            acc1 += to2(xv.x, xv.x) * w1 + to2(xv.y, xv.y) * to2(-w1.y, w1.x);
        }
    }
    int h = h0 + hg * 2, b = b0 + bl;
    acc0 += to2(biasR[h], biasI[h]);
    acc1 += to2(biasR[h + 1], biasI[h + 1]);
    ((float4*)(ws + IH_OFF))[b * 512 + (h >> 1)] =
        make_float4(acc0.x, acc0.y, acc1.x, acc1.y);
}

// ---------------------------------------------------------------------------
// mesh: 4 waves per batch row, 4 channels/lane. ALL boundary exchange
// (intra- and inter-wave) via one uniform LDS round-trip per step:
// every lane publishes post-A x[0], x[3]; raw s_barrier (NO vmcnt drain --
// table prefetch loads stay in flight across it, compiler emits counted
// vmcnt); every lane reads neighbors. Parity double-buffered slots; the
// manual lgkmcnt(0) drain before each barrier makes 2 slots race-free.
// ---------------------------------------------------------------------------
__device__ __forceinline__ void mzi(const float4 t, v2& a, v2& b)
{
    // p = e^{i t0} a ; a' = c1 p + i s1 b ; b' = i s1 p + c1 b
    v2 P  = to2(t.x, t.y) * to2(a.x, a.x) + to2(-t.y, t.x) * to2(a.y, a.y);
    v2 na = to2(t.z, t.z) * P + to2(-t.w, t.w) * to2(b.y, b.x);
    b     = to2(t.z, t.z) * b + to2(-t.w, t.w) * to2(P.y, P.x);
    a = na;
}

__device__ __forceinline__ void stepf(v2 x[4], const float4* T, const float4 TL,
                                      int g, int par,
                                      v2 (*sx0)[256], v2 (*sx3)[256])
{
    // A layer: both pairs lane-local
    mzi(T[0], x[0], x[1]);
    mzi(T[1], x[2], x[3]);
    // publish post-A boundary values (uniform, all lanes)
    sx0[par][g] = x[0];
    sx3[par][g] = x[3];
    // B local pair (ch 4g+1,4g+2) -- independent; covers the LDS-write drain
    mzi(T[2], x[1], x[2]);
    __asm__ volatile("s_waitcnt lgkmcnt(0)" ::: "memory");   // writes visible
    __builtin_amdgcn_sched_barrier(0);
    __builtin_amdgcn_s_barrier();                            // raw: no vmcnt drain
    __builtin_amdgcn_sched_barrier(0);
    // neighbor post-A values (edge lanes read wrapped garbage, but their
    // angle entries are identity -> multiplied by s=0)
    v2 rc = sx0[par][(g + 1) & 255];
    v2 lc = sx3[par][(g - 1) & 255];
    // right boundary: a-side update of x[3] (pair 2g+1) with right's x0
    {
        const float4 t = T[3];   // g=255: identity
        v2 P = to2(t.x, t.y) * to2(x[3].x, x[3].x) + to2(-t.y, t.x) * to2(x[3].y, x[3].y);
        x[3] = to2(t.z, t.z) * P + to2(-t.w, t.w) * to2(rc.y, rc.x);
    }
    // left boundary: b-side update of x[0] (pair 2g-1) with left's x3
    {
        // TL: g=0 -> identity
        v2 P = to2(TL.x, TL.y) * to2(lc.x, lc.x) + to2(-TL.y, TL.x) * to2(lc.y, lc.y);
        x[0] = to2(TL.z, TL.z) * x[0] + to2(-TL.w, TL.w) * to2(P.y, P.x);
    }
}

#define LOADL(T, TL, l)                                                   \
    do {                                                                  \
        const float4* _p = tab + (l) * TAB_F4_PER_L + g;                  \
        T[0] = _p[0];                                                     \
        T[1] = _p[256];                                                   \
        T[2] = _p[512];                                                   \
        T[3] = _p[768];                                                   \
        TL = _p[767];                       /* (j=3, g-1) */              \
        if (g == 0) TL = make_float4(1.f, 0.f, 1.f, 0.f);                 \
    } while (0)

__global__ __launch_bounds__(256, 1) void mesh_kernel(
    const float* __restrict__ stateR, const float* __restrict__ stateI,
    const float* __restrict__ omega,  const float* __restrict__ mod_bias,
    const float* __restrict__ ws, float* __restrict__ out)
{
    const int b = blockIdx.x;
    const int g = threadIdx.x;         // global lane 0..255, channels 4g..4g+3
    const float4* tab = (const float4*)ws;

    __shared__ v2 sx0[2][256];
    __shared__ v2 sx3[2][256];

    v2 x[4];
    {
        float4 r = *(const float4*)(stateR + b * NH + 4 * g);
        float4 i = *(const float4*)(stateI + b * NH + 4 * g);
        x[0] = to2(r.x, i.x);
        x[1] = to2(r.y, i.y);
        x[2] = to2(r.z, i.z);
        x[3] = to2(r.w, i.w);
    }

    float4 Ta[4], Tb[4], TLa, TLb;
    LOADL(Ta, TLa, 0);
    for (int l = 0; l < NSTEPS; l += 2) {
        LOADL(Tb, TLb, l + 1);
        stepf(x, Ta, TLa, g, 0, sx0, sx3);
        {
            int ln = (l + 2 < NSTEPS) ? l + 2 : NSTEPS - 1;
            LOADL(Ta, TLa, ln);
        }
        stepf(x, Tb, TLb, g, 1, sx0, sx3);
    }

    // epilogue: phase, + ih, modReLU  (channels 4g..4g+3)
    float4 o4 = *(const float4*)(omega + 4 * g);
    float4 m4 = *(const float4*)(mod_bias + 4 * g);
    const float4* ihp = (const float4*)(ws + IH_OFF) + b * 512 + 2 * g;
    float4 ih0 = ihp[0], ih1 = ihp[1];   // {R,I,R,I} ch 4g,4g+1 / 4g+2,4g+3

    float om[4] = { o4.x, o4.y, o4.z, o4.w };
    float mb[4] = { m4.x, m4.y, m4.z, m4.w };
    float ihr[4] = { ih0.x, ih0.z, ih1.x, ih1.z };
    float ihi[4] = { ih0.y, ih0.w, ih1.y, ih1.w };
    float oR[4], oI[4];
#pragma unroll
    for (int j = 0; j < 4; ++j) {
        float so, co;
        __sincosf(om[j], &so, &co);
        float zr = ihr[j] + co * x[j].x - so * x[j].y;
        float zi = ihi[j] + so * x[j].x + co * x[j].y;
        float mag = sqrtf(zr * zr + zi * zi);
        float sc = fmaxf(mag + mb[j], 0.f) / fmaxf(mag, 1e-8f);
        oR[j] = sc * zr;
        oI[j] = sc * zi;
    }
    *(float4*)(out + b * NH + 4 * g) = make_float4(oR[0], oR[1], oR[2], oR[3]);
    *(float4*)(out + NBATCH * NH + b * NH + 4 * g) = make_float4(oI[0], oI[1], oI[2], oI[3]);
}

// ---------------------------------------------------------------------------
extern "C" void kernel_launch(void* const* d_in, const int* in_sizes, int n_in,
                              void* d_out, int out_size, void* d_ws, size_t ws_size,
                              hipStream_t stream)
{
    const float* inputsR = (const float*)d_in[0];
    const float* inputsI = (const float*)d_in[1];
    const float* stateR  = (const float*)d_in[2];
    const float* stateI  = (const float*)d_in[3];
    const float* weightR = (const float*)d_in[4];
    const float* weightI = (const float*)d_in[5];
    const float* biasR   = (const float*)d_in[6];
    const float* biasI   = (const float*)d_in[7];
    const float* angleA0 = (const float*)d_in[8];
    const float* angleA1 = (const float*)d_in[9];
    const float* angleB0 = (const float*)d_in[10];
    const float* angleB1 = (const float*)d_in[11];
    const float* omega   = (const float*)d_in[12];
    const float* mod_b   = (const float*)d_in[13];
    float* ws = (float*)d_ws;
    float* out = (float*)d_out;

    hipLaunchKernelGGL(prep_kernel, dim3(GEMM_BLOCKS + TRIG_BLOCKS), dim3(256),
                       0, stream, inputsR, inputsI, weightR, weightI,
                       biasR, biasI, angleA0, angleA1, angleB0, angleB1, ws);
    hipLaunchKernelGGL(mesh_kernel, dim3(NBATCH), dim3(256), 0, stream,
                       stateR, stateI, omega, mod_b, ws, out);
}

// Round 4
// 150.961 us; speedup vs baseline: 1.4441x; 1.0753x over previous
//
#include <hip/hip_runtime.h>
#include <math.h>

typedef float v2 __attribute__((ext_vector_type(2)));

// B=128, IN=256, H=1024 -> 128 steps of (layerA, layerB). nA=512, nB=511.
#define NBATCH 128
#define NIN    256
#define NH     1024
#define NSTEPS 128
#define NB     511

// Angle table: [layer][j(0..3)][g(0..255)] float4 {c0,s0,c1,s1}
//   g = global lane (4 waves x 64 lanes), owns channels 4g..4g+3
//   j=0: A pair 2g     (ch 4g,4g+1)
//   j=1: A pair 2g+1   (ch 4g+2,4g+3)
//   j=2: B pair 2g     (ch 4g+1,4g+2)   always valid (2g <= 510)
//   j=3: B pair 2g+1   (ch 4g+3,4g+4)   g=255 -> pair 511 -> identity
// Left-boundary angle for lane g is entry (j=3, g-1): loaded directly
// (prefetchable). Table = 2 MB; ih = 1 MB.
#define TAB_F4_PER_L 1024
#define IH_OFF (NSTEPS * TAB_F4_PER_L * 4)   // float offset; ih float4 = {R,I,R,I}

#define GEMM_BLOCKS 256
#define TRIG_BLOCKS 512                      // 512*256 = 128*1024 exactly

static __device__ __forceinline__ v2 to2(float a, float b) { v2 r; r.x = a; r.y = b; return r; }

// ---------------------------------------------------------------------------
// prep: blocks [0,256) complex gemm ih = in @ W^T + bias; [256,768) trig table
// ---------------------------------------------------------------------------
__global__ __launch_bounds__(256) void prep_kernel(
    const float* __restrict__ inR, const float* __restrict__ inI,
    const float* __restrict__ wR,  const float* __restrict__ wI,
    const float* __restrict__ biasR, const float* __restrict__ biasI,
    const float* __restrict__ A0, const float* __restrict__ A1,
    const float* __restrict__ B0, const float* __restrict__ B1,
    float* __restrict__ ws)
{
    __shared__ v2 xs[256][17];   // [k][b]  {xr,xi}
    __shared__ v2 wsh[32][34];   // [k][h]  {wr,wi}; stride 34 v2 = 272 B (16-aligned rows)

    if (blockIdx.x >= GEMM_BLOCKS) {
        // ---------------- trig branch ----------------
        int idx = (blockIdx.x - GEMM_BLOCKS) * 256 + threadIdx.x;
        int l = idx >> 10;
        int s = idx & 1023;
        int j = s >> 8, g = s & 255;
        float a0, a1;
        bool ident = false;
        if (j < 2) {
            int p = 2 * g + j;                    // A pair, always < 512
            a0 = A0[l * 512 + p]; a1 = A1[l * 512 + p];
        } else {
            int p = 2 * g + (j - 2);              // B pair
            if (p < NB) { a0 = B0[l * NB + p]; a1 = B1[l * NB + p]; }
            else ident = true;
        }
        float4 v;
        if (ident) v = make_float4(1.f, 0.f, 1.f, 0.f);
        else {
            float s0, c0, s1, c1;
            __sincosf(a0, &s0, &c0);
            __sincosf(a1, &s1, &c1);
            v = make_float4(c0, s0, c1, s1);
        }
        ((float4*)ws)[l * TAB_F4_PER_L + j * 256 + g] = v;
        return;
    }

    // ---------------- gemm branch: 32h x 16b tile ----------------
    const int ht = blockIdx.x >> 3, bt = blockIdx.x & 7;
    const int h0 = ht * 32, b0 = bt * 16;
    const int tid = threadIdx.x;

    // stage inputs for 16 batch rows: xs[k][b] = {inR, inI}
    {
        int b = tid >> 4, k4 = tid & 15;
#pragma unroll
        for (int p = 0; p < 4; ++p) {
            int k0 = p * 64 + k4 * 4;
            float4 vr = *(const float4*)(inR + (b0 + b) * NIN + k0);
            float4 vi = *(const float4*)(inI + (b0 + b) * NIN + k0);
            xs[k0 + 0][b] = to2(vr.x, vi.x);
            xs[k0 + 1][b] = to2(vr.y, vi.y);
            xs[k0 + 2][b] = to2(vr.z, vi.z);
            xs[k0 + 3][b] = to2(vr.w, vi.w);
        }
    }

    const int hg = tid & 15, bl = tid >> 4;   // thread: 2 h (h0+2hg, +1), 1 b
    v2 acc0 = to2(0.f, 0.f), acc1 = to2(0.f, 0.f);

    for (int c = 0; c < 8; ++c) {
        __syncthreads();
        // stage weight chunk: 32 h x 32 k as {wr,wi}
        {
            int hh = tid >> 3, k4 = tid & 7;
            float4 vr = *(const float4*)(wR + (h0 + hh) * NIN + c * 32 + k4 * 4);
            float4 vi = *(const float4*)(wI + (h0 + hh) * NIN + c * 32 + k4 * 4);
            wsh[k4 * 4 + 0][hh] = to2(vr.x, vi.x);
            wsh[k4 * 4 + 1][hh] = to2(vr.y, vi.y);
            wsh[k4 * 4 + 2][hh] = to2(vr.z, vi.z);
            wsh[k4 * 4 + 3][hh] = to2(vr.w, vi.w);
        }
        __syncthreads();
#pragma unroll
        for (int k = 0; k < 32; ++k) {
            float4 wv = *(const float4*)&wsh[k][hg * 2];   // {wr0,wi0,wr1,wi1}
            v2 w0 = to2(wv.x, wv.y), w1 = to2(wv.z, wv.w);
            v2 xv = xs[c * 32 + k][bl];
            acc0 += to2(xv.x, xv.x) * w0 + to2(xv.y, xv.y) * to2(-w0.y, w0.x);
            acc1 += to2(xv.x, xv.x) * w1 + to2(xv.y, xv.y) * to2(-w1.y, w1.x);
        }
    }
    int h = h0 + hg * 2, b = b0 + bl;
    acc0 += to2(biasR[h], biasI[h]);
    acc1 += to2(biasR[h + 1], biasI[h + 1]);
    ((float4*)(ws + IH_OFF))[b * 512 + (h >> 1)] =
        make_float4(acc0.x, acc0.y, acc1.x, acc1.y);
}

// ---------------------------------------------------------------------------
// mesh: 4 waves per batch row, 4 channels/lane (round-1 structure: shuffles
// for intra-wave, exec-masked edge-lane LDS for inter-wave). ONE change vs
// round 1: raw s_barrier with lgkmcnt(0)-only drain -- the 5 table-prefetch
// global loads stay in flight across the barrier (compiler emits counted
// vmcnt at first use). Shuffles + independent B-MZI placed AFTER the
// barrier so they cover the edge-lane LDS read latency.
// ---------------------------------------------------------------------------
__device__ __forceinline__ void mzi(const float4 t, v2& a, v2& b)
{
    // p = e^{i t0} a ; a' = c1 p + i s1 b ; b' = i s1 p + c1 b
    v2 P  = to2(t.x, t.y) * to2(a.x, a.x) + to2(-t.y, t.x) * to2(a.y, a.y);
    v2 na = to2(t.z, t.z) * P + to2(-t.w, t.w) * to2(b.y, b.x);
    b     = to2(t.z, t.z) * b + to2(-t.w, t.w) * to2(P.y, P.x);
    a = na;
}

// boundary bd (0..2) sits between wave bd and wave bd+1.
// sx0[par][bd] = post-A x[0] of wave bd+1 (lane 0)  -> read by wave bd lane 63
// sx3[par][bd] = post-A x[3] of wave bd   (lane 63) -> read by wave bd+1 lane 0
__device__ __forceinline__ void stepf(v2 x[4], const float4* T, const float4 TL,
                                      int w, int lane, int par,
                                      v2 (*sx0)[3], v2 (*sx3)[3])
{
    // A layer: both pairs lane-local
    mzi(T[0], x[0], x[1]);
    mzi(T[1], x[2], x[3]);
    // edge lanes publish post-A boundary values
    if (lane == 0 && w > 0)  sx0[par][w - 1] = x[0];
    if (lane == 63 && w < 3) sx3[par][w] = x[3];
    __asm__ volatile("s_waitcnt lgkmcnt(0)" ::: "memory");   // writes visible
    __builtin_amdgcn_s_barrier();                            // raw: vmcnt stays in flight
    __asm__ volatile("" ::: "memory");                       // no hoisting reads above

    // intra-wave boundary values via shuffle (no barrier dependence)
    float rcr = __shfl_down(x[0].x, 1, 64);
    float rci = __shfl_down(x[0].y, 1, 64);
    float lcr = __shfl_up(x[3].x, 1, 64);
    float lci = __shfl_up(x[3].y, 1, 64);
    // edge lanes read neighbor values from LDS
    if (lane == 63 && w < 3) { v2 t = sx0[par][w]; rcr = t.x; rci = t.y; }
    if (lane == 0 && w > 0)  { v2 t = sx3[par][w - 1]; lcr = t.x; lci = t.y; }

    // B local pair (ch 4g+1, 4g+2) -- independent of boundary data; covers
    // the shuffle/LDS-read latency
    mzi(T[2], x[1], x[2]);

    // right boundary: a-side update of x[3] with right neighbor's post-A x0
    {
        const float4 t = T[3];   // g=255: identity from table
        v2 P = to2(t.x, t.y) * to2(x[3].x, x[3].x) + to2(-t.y, t.x) * to2(x[3].y, x[3].y);
        x[3] = to2(t.z, t.z) * P + to2(-t.w, t.w) * to2(rci, rcr);
    }
    // left boundary: b-side update of x[0] with left neighbor's post-A x3
    {
        // TL: g=0 -> identity
        v2 P = to2(TL.x, TL.y) * to2(lcr, lcr) + to2(-TL.y, TL.x) * to2(lci, lci);
        x[0] = to2(TL.z, TL.z) * x[0] + to2(-TL.w, TL.w) * to2(P.y, P.x);
    }
}

#define LOADL(T, TL, l)                                                   \
    do {                                                                  \
        const float4* _p = tab + (l) * TAB_F4_PER_L + g;                  \
        T[0] = _p[0];                                                     \
        T[1] = _p[256];                                                   \
        T[2] = _p[512];                                                   \
        T[3] = _p[768];                                                   \
        TL = _p[767];                       /* (j=3, g-1) */              \
        if (g == 0) TL = make_float4(1.f, 0.f, 1.f, 0.f);                 \
    } while (0)

__global__ __launch_bounds__(256, 1) void mesh_kernel(
    const float* __restrict__ stateR, const float* __restrict__ stateI,
    const float* __restrict__ omega,  const float* __restrict__ mod_bias,
    const float* __restrict__ ws, float* __restrict__ out)
{
    const int b = blockIdx.x;
    const int g = threadIdx.x;         // global lane 0..255, channels 4g..4g+3
    const int lane = g & 63;
    const int w = g >> 6;
    const float4* tab = (const float4*)ws;

    __shared__ v2 sx0[2][3];
    __shared__ v2 sx3[2][3];

    v2 x[4];
    {
        float4 r = *(const float4*)(stateR + b * NH + 4 * g);
        float4 i = *(const float4*)(stateI + b * NH + 4 * g);
        x[0] = to2(r.x, i.x);
        x[1] = to2(r.y, i.y);
        x[2] = to2(r.z, i.z);
        x[3] = to2(r.w, i.w);
    }

    float4 Ta[4], Tb[4], TLa, TLb;
    LOADL(Ta, TLa, 0);
    for (int l = 0; l < NSTEPS; l += 2) {
        LOADL(Tb, TLb, l + 1);
        stepf(x, Ta, TLa, w, lane, 0, sx0, sx3);
        {
            int ln = (l + 2 < NSTEPS) ? l + 2 : NSTEPS - 1;
            LOADL(Ta, TLa, ln);
        }
        stepf(x, Tb, TLb, w, lane, 1, sx0, sx3);
    }

    // epilogue: phase, + ih, modReLU  (channels 4g..4g+3)
    float4 o4 = *(const float4*)(omega + 4 * g);
    float4 m4 = *(const float4*)(mod_bias + 4 * g);
    const float4* ihp = (const float4*)(ws + IH_OFF) + b * 512 + 2 * g;
    float4 ih0 = ihp[0], ih1 = ihp[1];   // {R,I,R,I} ch 4g,4g+1 / 4g+2,4g+3

    float om[4] = { o4.x, o4.y, o4.z, o4.w };
    float mb[4] = { m4.x, m4.y, m4.z, m4.w };
    float ihr[4] = { ih0.x, ih0.z, ih1.x, ih1.z };
    float ihi[4] = { ih0.y, ih0.w, ih1.y, ih1.w };
    float oR[4], oI[4];
#pragma unroll
    for (int j = 0; j < 4; ++j) {
        float so, co;
        __sincosf(om[j], &so, &co);
        float zr = ihr[j] + co * x[j].x - so * x[j].y;
        float zi = ihi[j] + so * x[j].x + co * x[j].y;
        float mag = sqrtf(zr * zr + zi * zi);
        float sc = fmaxf(mag + mb[j], 0.f) / fmaxf(mag, 1e-8f);
        oR[j] = sc * zr;
        oI[j] = sc * zi;
    }
    *(float4*)(out + b * NH + 4 * g) = make_float4(oR[0], oR[1], oR[2], oR[3]);
    *(float4*)(out + NBATCH * NH + b * NH + 4 * g) = make_float4(oI[0], oI[1], oI[2], oI[3]);
}

// ---------------------------------------------------------------------------
extern "C" void kernel_launch(void* const* d_in, const int* in_sizes, int n_in,
                              void* d_out, int out_size, void* d_ws, size_t ws_size,
                              hipStream_t stream)
{
    const float* inputsR = (const float*)d_in[0];
    const float* inputsI = (const float*)d_in[1];
    const float* stateR  = (const float*)d_in[2];
    const float* stateI  = (const float*)d_in[3];
    const float* weightR = (const float*)d_in[4];
    const float* weightI = (const float*)d_in[5];
    const float* biasR   = (const float*)d_in[6];
    const float* biasI   = (const float*)d_in[7];
    const float* angleA0 = (const float*)d_in[8];
    const float* angleA1 = (const float*)d_in[9];
    const float* angleB0 = (const float*)d_in[10];
    const float* angleB1 = (const float*)d_in[11];
    const float* omega   = (const float*)d_in[12];
    const float* mod_b   = (const float*)d_in[13];
    float* ws = (float*)d_ws;
    float* out = (float*)d_out;

    hipLaunchKernelGGL(prep_kernel, dim3(GEMM_BLOCKS + TRIG_BLOCKS), dim3(256),
                       0, stream, inputsR, inputsI, weightR, weightI,
                       biasR, biasI, angleA0, angleA1, angleB0, angleB1, ws);
    hipLaunchKernelGGL(mesh_kernel, dim3(NBATCH), dim3(256), 0, stream,
                       stateR, stateI, omega, mod_b, ws, out);
}